// Round 16
// baseline (187.940 us; speedup 1.0000x reference)
//
#include <hip/hip_runtime.h>

#define TOK 4096
#define EMB 1024

typedef __attribute__((ext_vector_type(8))) short s16x8;
typedef __attribute__((ext_vector_type(4))) float f32x4;

__device__ __forceinline__ unsigned short f2bf(float f) {
  union { float f; unsigned int u; } v; v.f = f;
  unsigned int r = v.u + 0x7FFFu + ((v.u >> 16) & 1u);
  return (unsigned short)(r >> 16);
}
__device__ __forceinline__ float bf2f(unsigned short u) {
  union { unsigned int u; float f; } v; v.u = ((unsigned int)u) << 16; return v.f;
}

#define GLOAD_LDS16(g, l) __builtin_amdgcn_global_load_lds( \
    (const __attribute__((address_space(1))) void*)(g), \
    (__attribute__((address_space(3))) void*)(l), 16, 0, 0)

// =================== 256x256 GEMM (round-9 core, FROZEN at ~868 TF)
// 512 threads = 8 waves (2M x 4N), per-wave out 128x64, BK=64, dbuf LDS 128KB.
// NT template -> fully unrolled K-loop, hoisted LDS read bases (kt&1)<<15.
// PART: 0 = bias(+relu) -> bf16 store; 1 = bf16 partial store at C + y*M*N.
// VTR:  1 = QKV mode: for output cols >= 2048 (the V third), ALSO store the
//       value transposed into vT[dcol][token] (ushort4-packed along tokens).
// Round-10 lesson: fp32 atomicAdd epilogue = 2x kernel time (L2 RMW). Do not revisit.
// Round-13 lesson: cooperative grid.sync()+in-kernel reduce = 4x GEMM slowdown.
// Round-15 lesson: swizzle read must XOR the FULL slot index (incl. the ks
//   bit), not a partial term with the rest added — rule #21 both-sides-same-involution.
template<int RELU, int PART, int NT, int VTR>
__global__ __launch_bounds__(512)
void gemm256(const unsigned short* __restrict__ A,
             const unsigned short* __restrict__ B,
             const float* __restrict__ bias,
             unsigned short* __restrict__ C, int M, int N, int K,
             unsigned short* __restrict__ vT)
{
  __shared__ unsigned short lds[2][2][128 * 128];  // [matrix][buf][16384 shorts]
  const int tid = threadIdx.x;
  const int lane = tid & 63;
  const int w = tid >> 6;
  const int wr = w >> 2, wc = w & 3;
  const int l15 = lane & 15, lhi = lane >> 4;
  const int nbm = M >> 8;
  const int bm = blockIdx.x % nbm, bn = blockIdx.x / nbm;
  const int m0 = bm << 8, n0 = bn << 8;
  const int k0 = blockIdx.y * (NT * 64);

  const char* Abase = (const char*)(A + (size_t)m0 * K) + (size_t)k0 * 2;
  const char* Bbase = (const char*)(B + (size_t)n0 * K) + (size_t)k0 * 2;
  const size_t rowb = (size_t)K * 2;

  const int srt = tid >> 3;
  const int sccx = ((tid & 7) << 4) ^ ((srt & 7) << 4);
  const char* gA = Abase + (size_t)srt * rowb + sccx;
  const char* gB = Bbase + (size_t)srt * rowb + sccx;

  auto STAGE_A = [&](int ktl, int h, int p) {
    char* d = (char*)&lds[0][0][0] + p * 32768 + h * 16384 + (w << 10);
    const char* g = gA + (size_t)(h * 128) * rowb + ktl * 128;
    GLOAD_LDS16(g, d);
    GLOAD_LDS16(g + 64 * rowb, d + 8192);
  };
  auto STAGE_B = [&](int ktl, int h, int p) {
    char* d = (char*)&lds[1][0][0] + p * 32768 + h * 16384 + (w << 10);
    const char* g = gB + (size_t)(h * 128) * rowb + ktl * 128;
    GLOAD_LDS16(g, d);
    GLOAD_LDS16(g + 64 * rowb, d + 8192);
  };

  const int rdxor = (l15 & 7) << 4;
  const char* pA0 = (const char*)&lds[0][0][0] + (wr * 128 + l15) * 128 + ((0 * 64 + lhi * 16) ^ rdxor);
  const char* pA1 = (const char*)&lds[0][0][0] + (wr * 128 + l15) * 128 + ((1 * 64 + lhi * 16) ^ rdxor);
  const char* pB0 = (const char*)&lds[1][0][0] + (wc * 64 + l15) * 128 + ((0 * 64 + lhi * 16) ^ rdxor);
  const char* pB1 = (const char*)&lds[1][0][0] + (wc * 64 + l15) * 128 + ((1 * 64 + lhi * 16) ^ rdxor);

  f32x4 acc[8][4];
#pragma unroll
  for (int mf = 0; mf < 8; ++mf)
#pragma unroll
    for (int nf = 0; nf < 4; ++nf)
#pragma unroll
      for (int j = 0; j < 4; ++j) acc[mf][nf][j] = 0.f;

  STAGE_A(0, 0, 0); STAGE_A(0, 1, 0);
  STAGE_B(0, 0, 0); STAGE_B(0, 1, 0);
  STAGE_A(1, 0, 1); STAGE_A(1, 1, 1);
  STAGE_B(1, 0, 1);
  asm volatile("s_waitcnt vmcnt(6)" ::: "memory");
  __builtin_amdgcn_s_barrier();

  s16x8 af[8][2], bf[4][2];

#pragma unroll
  for (int kt = 0; kt < NT; ++kt) {
    const int P = (kt & 1) << 15;
    const int p = kt & 1;

#pragma unroll
    for (int mi = 0; mi < 4; ++mi) {
      af[mi][0] = *(const s16x8*)(pA0 + mi * 2048 + P);
      af[mi][1] = *(const s16x8*)(pA1 + mi * 2048 + P);
    }
#pragma unroll
    for (int ni = 0; ni < 2; ++ni) {
      bf[ni][0] = *(const s16x8*)(pB0 + ni * 2048 + P);
      bf[ni][1] = *(const s16x8*)(pB1 + ni * 2048 + P);
    }
#pragma unroll
    for (int mi = 4; mi < 8; ++mi) {
      af[mi][0] = *(const s16x8*)(pA0 + mi * 2048 + P);
      af[mi][1] = *(const s16x8*)(pA1 + mi * 2048 + P);
    }
#pragma unroll
    for (int ni = 2; ni < 4; ++ni) {
      bf[ni][0] = *(const s16x8*)(pB0 + ni * 2048 + P);
      bf[ni][1] = *(const s16x8*)(pB1 + ni * 2048 + P);
    }

    if (kt + 1 < NT) STAGE_B(kt + 1, 1, p ^ 1);

    __builtin_amdgcn_s_setprio(1);
#pragma unroll
    for (int mi = 0; mi < 4; ++mi)
#pragma unroll
      for (int ni = 0; ni < 2; ++ni)
#pragma unroll
        for (int ks = 0; ks < 2; ++ks)
          acc[mi][ni] = __builtin_amdgcn_mfma_f32_16x16x32_bf16(af[mi][ks], bf[ni][ks], acc[mi][ni], 0, 0, 0);
#pragma unroll
    for (int mi = 4; mi < 8; ++mi)
#pragma unroll
      for (int ni = 0; ni < 2; ++ni)
#pragma unroll
        for (int ks = 0; ks < 2; ++ks)
          acc[mi][ni] = __builtin_amdgcn_mfma_f32_16x16x32_bf16(af[mi][ks], bf[ni][ks], acc[mi][ni], 0, 0, 0);
#pragma unroll
    for (int mi = 0; mi < 4; ++mi)
#pragma unroll
      for (int ni = 2; ni < 4; ++ni)
#pragma unroll
        for (int ks = 0; ks < 2; ++ks)
          acc[mi][ni] = __builtin_amdgcn_mfma_f32_16x16x32_bf16(af[mi][ks], bf[ni][ks], acc[mi][ni], 0, 0, 0);
#pragma unroll
    for (int mi = 4; mi < 8; ++mi)
#pragma unroll
      for (int ni = 2; ni < 4; ++ni)
#pragma unroll
        for (int ks = 0; ks < 2; ++ks)
          acc[mi][ni] = __builtin_amdgcn_mfma_f32_16x16x32_bf16(af[mi][ks], bf[ni][ks], acc[mi][ni], 0, 0, 0);
    __builtin_amdgcn_s_setprio(0);

    __builtin_amdgcn_s_barrier();

    if (kt + 2 < NT) {
      STAGE_A(kt + 2, 0, p);
      STAGE_A(kt + 2, 1, p);
      STAGE_B(kt + 2, 0, p);
    }

    if (kt + 1 < NT) {
      if (kt + 2 < NT) asm volatile("s_waitcnt vmcnt(6)" ::: "memory");
      else             asm volatile("s_waitcnt vmcnt(0)" ::: "memory");
      __builtin_amdgcn_s_barrier();
    }
  }

  // ---- epilogue
  unsigned short* Cw = PART ? C + (size_t)blockIdx.y * M * N : C;
#pragma unroll
  for (int mf = 0; mf < 8; ++mf) {
    const int row = m0 + wr * 128 + mf * 16 + lhi * 4;
#pragma unroll
    for (int nf = 0; nf < 4; ++nf) {
      const int col = n0 + wc * 64 + nf * 16 + l15;
      const float bv = PART ? 0.f : bias[col];
      ushort4 pk;
#pragma unroll
      for (int j = 0; j < 4; ++j) {
        float v = acc[mf][nf][j] + bv;
        if (RELU) v = fmaxf(v, 0.f);
        const unsigned short bb = f2bf(v);
        Cw[(size_t)(row + j) * N + col] = bb;
        if (VTR) { if (j == 0) pk.x = bb; else if (j == 1) pk.y = bb; else if (j == 2) pk.z = bb; else pk.w = bb; }
      }
      if (VTR && col >= 2048) {
        const int dcol = col - 2048;
        *(ushort4*)(vT + (size_t)dcol * 4096 + row) = pk;
      }
    }
  }
}

// ---------------- reduce split-K partials + bias + residual(bf16) -> fp32 out
__global__ __launch_bounds__(256)
void reduce_add(const unsigned short* __restrict__ part, const unsigned short* __restrict__ res,
                const float* __restrict__ bias, float* __restrict__ out,
                int MN, int N, int S)
{
  const int i4 = (blockIdx.x * 256 + threadIdx.x) * 4;
  if (i4 >= MN) return;
  const int col = i4 & (N - 1);
  const ushort4 r = *(const ushort4*)(res + i4);
  float4 v;
  v.x = bf2f(r.x) + bias[col];
  v.y = bf2f(r.y) + bias[col + 1];
  v.z = bf2f(r.z) + bias[col + 2];
  v.w = bf2f(r.w) + bias[col + 3];
  for (int s = 0; s < S; ++s) {
    const ushort4 p = *(const ushort4*)(part + (size_t)s * MN + i4);
    v.x += bf2f(p.x); v.y += bf2f(p.y); v.z += bf2f(p.z); v.w += bf2f(p.w);
  }
  *(float4*)(out + i4) = v;
}

// ---------------- reduce out-proj partials + bias + residual, then LayerNorm2
__global__ __launch_bounds__(256)
void reduce_ln(const unsigned short* __restrict__ part, const float* __restrict__ x,
               const float* __restrict__ ob, const float* __restrict__ ln_w,
               const float* __restrict__ ln_b, unsigned short* __restrict__ h2,
               unsigned short* __restrict__ m_in, int S)
{
  const int row = blockIdx.x;
  const int t = threadIdx.x;
  const size_t off = (size_t)row * EMB + t * 4;
  float4 v = *(const float4*)(x + off);
  const float4 obv = ((const float4*)ob)[t];
  v.x += obv.x; v.y += obv.y; v.z += obv.z; v.w += obv.w;
  for (int s = 0; s < S; ++s) {
    const ushort4 p = *(const ushort4*)(part + (size_t)s * TOK * EMB + off);
    v.x += bf2f(p.x); v.y += bf2f(p.y); v.z += bf2f(p.z); v.w += bf2f(p.w);
  }
  ushort4 hb;
  hb.x = f2bf(v.x); hb.y = f2bf(v.y); hb.z = f2bf(v.z); hb.w = f2bf(v.w);
  *(ushort4*)(h2 + off) = hb;

  float s1 = v.x + v.y + v.z + v.w;
  float sq = v.x * v.x + v.y * v.y + v.z * v.z + v.w * v.w;
#pragma unroll
  for (int o = 1; o < 64; o <<= 1) { s1 += __shfl_xor(s1, o); sq += __shfl_xor(sq, o); }
  __shared__ float red[8];
  if ((t & 63) == 0) { red[t >> 6] = s1; red[4 + (t >> 6)] = sq; }
  __syncthreads();
  s1 = red[0] + red[1] + red[2] + red[3];
  sq = red[4] + red[5] + red[6] + red[7];
  const float mu = s1 * (1.f / EMB);
  const float rs = rsqrtf(sq * (1.f / EMB) - mu * mu + 1e-5f);
  const float4 wv = ((const float4*)ln_w)[t];
  const float4 bv = ((const float4*)ln_b)[t];
  ushort4 o;
  o.x = f2bf((v.x - mu) * rs * wv.x + bv.x);
  o.y = f2bf((v.y - mu) * rs * wv.y + bv.y);
  o.z = f2bf((v.z - mu) * rs * wv.z + bv.z);
  o.w = f2bf((v.w - mu) * rs * wv.w + bv.w);
  ((ushort4*)(m_in + (size_t)row * EMB))[t] = o;
}

// ---------------- prep: weight cvt (4 matrices) + LayerNorm1, one launch
#define Q0 786432
#define Q1 (Q0 + 262144)
#define Q2 (Q1 + 1048576)
#define Q3 (Q2 + 1048576)
#define CVT_BLOCKS (Q3 / 256)   // 12288
__global__ __launch_bounds__(256)
void prep(const float* __restrict__ w0, const float* __restrict__ w1s,
          const float* __restrict__ w2s, const float* __restrict__ w3s,
          unsigned short* __restrict__ d0, unsigned short* __restrict__ d1,
          unsigned short* __restrict__ d2, unsigned short* __restrict__ d3,
          const float* __restrict__ x, const float* __restrict__ ln_w,
          const float* __restrict__ ln_b, unsigned short* __restrict__ h)
{
  __shared__ float red[8];
  const int bid = blockIdx.x;
  const int t = threadIdx.x;
  if (bid < CVT_BLOCKS) {
    const int i = bid * 256 + t;
    const float* s; unsigned short* d; int off;
    if (i < Q0)      { s = w0;  d = d0; off = i; }
    else if (i < Q1) { s = w1s; d = d1; off = i - Q0; }
    else if (i < Q2) { s = w2s; d = d2; off = i - Q1; }
    else             { s = w3s; d = d3; off = i - Q2; }
    const float4 v = ((const float4*)s)[off];
    ushort4 o;
    o.x = f2bf(v.x); o.y = f2bf(v.y); o.z = f2bf(v.z); o.w = f2bf(v.w);
    ((ushort4*)d)[off] = o;
    return;
  }
  const int row = bid - CVT_BLOCKS;
  const float4 v = ((const float4*)(x + (size_t)row * EMB))[t];
  float sm = v.x + v.y + v.z + v.w;
  float sq = v.x * v.x + v.y * v.y + v.z * v.z + v.w * v.w;
#pragma unroll
  for (int off = 1; off < 64; off <<= 1) { sm += __shfl_xor(sm, off); sq += __shfl_xor(sq, off); }
  if ((t & 63) == 0) { red[t >> 6] = sm; red[4 + (t >> 6)] = sq; }
  __syncthreads();
  sm = red[0] + red[1] + red[2] + red[3];
  sq = red[4] + red[5] + red[6] + red[7];
  const float mu = sm * (1.f / EMB);
  const float rs = rsqrtf(sq * (1.f / EMB) - mu * mu + 1e-5f);
  const float4 wv = ((const float4*)ln_w)[t];
  const float4 bv = ((const float4*)ln_b)[t];
  ushort4 o;
  o.x = f2bf((v.x - mu) * rs * wv.x + bv.x);
  o.y = f2bf((v.y - mu) * rs * wv.y + bv.y);
  o.z = f2bf((v.z - mu) * rs * wv.z + bv.z);
  o.w = f2bf((v.w - mu) * rs * wv.w + bv.w);
  ((ushort4*)(h + (size_t)row * EMB))[t] = o;
}

// ---------------- sliding-window causal attention, flash-style
// V staged via global_load_lds from pre-transposed vT. Swizzle convention:
// LDS[d][slot s] holds global slot g = s ^ (d&7) (16B slots, byte bits 4-6).
// Read of logical slot g=ks*4+lhi must use s=(ks*4+lhi)^(d&7) — full-index XOR
// (round-15 bug: partial XOR + add corrupted rows with d&4).
__global__ __launch_bounds__(256)
void attn_win(const unsigned short* __restrict__ qkv, const unsigned short* __restrict__ vT,
              unsigned short* __restrict__ aout)
{
  __shared__ unsigned short Ks[64 * 136];   // K tile, padded
  __shared__ unsigned short Vt[128 * 64];   // V^T tile [d][t], swizzled, 16KB
  __shared__ unsigned short Ps[4 * 16 * 72];
  const int bh = blockIdx.y;
  const int b = bh >> 3, hh = bh & 7;
  const int q0 = blockIdx.x << 6;
  const int tid = threadIdx.x, lane = tid & 63, w = tid >> 6;
  const int l15 = lane & 15, lhi = lane >> 4;
  const size_t base = (size_t)b * 2048 * 3072;

  s16x8 qf[4];
  {
    const unsigned short* qp = qkv + base + (size_t)(q0 + w * 16 + l15) * 3072 + hh * 128 + lhi * 8;
#pragma unroll
    for (int ks = 0; ks < 4; ++ks) qf[ks] = *(const s16x8*)(qp + ks * 32);
  }

  // V staging: call c covers d-rows c*32..c*32+31. Thread t -> LDS byte
  // c*4096 + t*16 = row (c*32 + (t>>3)), slot (t&7). Source col pre-XOR'd:
  // ((t&7) ^ ((t>>3)&7))<<4 (row-invariant across c since c*32 % 8 == 0).
  const int vrow = tid >> 3;
  const int vcol = (((tid & 7) ^ ((tid >> 3) & 7)) << 4);
  const char* vTbase = (const char*)(vT + (size_t)(hh * 128 + vrow) * 4096) + vcol;
  char* vdst = (char*)&Vt[0] + (w << 10);          // wave-uniform LDS base
  // PV read: row base only; column computed per (ks,lhi) with full-index XOR
  const char* pVrow = (const char*)&Vt[0] + l15 * 128;
  const int vxor = (l15 & 7) << 4;

  f32x4 o[8];
#pragma unroll
  for (int n = 0; n < 8; ++n)
#pragma unroll
    for (int j = 0; j < 4; ++j) o[n][j] = 0.f;
  float mrow[4] = {-1e30f, -1e30f, -1e30f, -1e30f};
  float lrow[4] = {0.f, 0.f, 0.f, 0.f};

  for (int t = 0; t < 5; ++t) {
    const int kt0 = q0 - 256 + t * 64;
    if (kt0 < 0) continue;
    __syncthreads();
    {
      const unsigned short* kg = qkv + base + (size_t)kt0 * 3072 + 1024 + hh * 128;
#pragma unroll
      for (int i = 0; i < 4; ++i) {
        const int c = tid + i * 256;
        const int r = c >> 4, cc = (c & 15) << 3;
        *(s16x8*)(Ks + r * 136 + cc) = *(const s16x8*)(kg + (size_t)r * 3072 + cc);
      }
      const char* vg = vTbase + (size_t)(b * 2048 + kt0) * 2;
#pragma unroll
      for (int c = 0; c < 4; ++c)
        GLOAD_LDS16(vg + (size_t)(c * 32) * 8192, vdst + c * 4096);
    }
    __syncthreads();

    f32x4 s[4];
#pragma unroll
    for (int n = 0; n < 4; ++n)
#pragma unroll
      for (int j = 0; j < 4; ++j) s[n][j] = 0.f;
    __builtin_amdgcn_s_setprio(1);
#pragma unroll
    for (int ks = 0; ks < 4; ++ks) {
#pragma unroll
      for (int n = 0; n < 4; ++n) {
        s16x8 kf = *(const s16x8*)(Ks + (n * 16 + l15) * 136 + ks * 32 + lhi * 8);
        s[n] = __builtin_amdgcn_mfma_f32_16x16x32_bf16(qf[ks], kf, s[n], 0, 0, 0);
      }
    }
    __builtin_amdgcn_s_setprio(0);
    const bool mlo = (t == 0);
    const bool mhi = (kt0 == q0);
#pragma unroll
    for (int n = 0; n < 4; ++n) {
      const int kcol = n * 16 + l15;
#pragma unroll
      for (int j = 0; j < 4; ++j) {
        const int qrow = w * 16 + lhi * 4 + j;
        float v = s[n][j] * 0.08838834764831845f;
        if ((mlo && kcol < qrow) || (mhi && kcol > qrow)) v = -1e30f;
        s[n][j] = v;
      }
    }
    float alpha[4];
#pragma unroll
    for (int j = 0; j < 4; ++j) {
      float mx = fmaxf(fmaxf(s[0][j], s[1][j]), fmaxf(s[2][j], s[3][j]));
#pragma unroll
      for (int off = 1; off < 16; off <<= 1) mx = fmaxf(mx, __shfl_xor(mx, off));
      const float mn = fmaxf(mrow[j], mx);
      alpha[j] = __expf(mrow[j] - mn);
      mrow[j] = mn;
    }
    float rowsum[4] = {0.f, 0.f, 0.f, 0.f};
#pragma unroll
    for (int n = 0; n < 4; ++n)
#pragma unroll
      for (int j = 0; j < 4; ++j) {
        const float p = __expf(s[n][j] - mrow[j]);
        rowsum[j] += p;
        Ps[(w * 16 + lhi * 4 + j) * 72 + n * 16 + l15] = f2bf(p);
      }
#pragma unroll
    for (int j = 0; j < 4; ++j) {
      float rs = rowsum[j];
#pragma unroll
      for (int off = 1; off < 16; off <<= 1) rs += __shfl_xor(rs, off);
      lrow[j] = lrow[j] * alpha[j] + rs;
    }
#pragma unroll
    for (int n = 0; n < 8; ++n)
#pragma unroll
      for (int j = 0; j < 4; ++j) o[n][j] *= alpha[j];
    __builtin_amdgcn_s_setprio(1);
#pragma unroll
    for (int ks = 0; ks < 2; ++ks) {
      const s16x8 pf = *(const s16x8*)(Ps + (w * 16 + l15) * 72 + ks * 32 + lhi * 8);
      const int cc = (ks * 64 + lhi * 16) ^ vxor;   // full-index XOR (r15 fix)
#pragma unroll
      for (int n = 0; n < 8; ++n) {
        const s16x8 vf = *(const s16x8*)(pVrow + n * 2048 + cc);
        o[n] = __builtin_amdgcn_mfma_f32_16x16x32_bf16(pf, vf, o[n], 0, 0, 0);
      }
    }
    __builtin_amdgcn_s_setprio(0);
  }
  unsigned short* op = aout + (size_t)(b * 2048 + q0 + w * 16) * 1024 + hh * 128;
#pragma unroll
  for (int n = 0; n < 8; ++n)
#pragma unroll
    for (int j = 0; j < 4; ++j)
      op[(size_t)(lhi * 4 + j) * 1024 + n * 16 + l15] = f2bf(o[n][j] / lrow[j]);
}

extern "C" void kernel_launch(void* const* d_in, const int* in_sizes, int n_in,
                              void* d_out, int out_size, void* d_ws, size_t ws_size,
                              hipStream_t stream)
{
  (void)in_sizes; (void)n_in; (void)out_size; (void)ws_size;
  const float* x         = (const float*)d_in[0];
  const float* ln1_w     = (const float*)d_in[1];
  const float* ln1_b     = (const float*)d_in[2];
  const float* ln2_w     = (const float*)d_in[3];
  const float* ln2_b     = (const float*)d_in[4];
  const float* in_proj_w = (const float*)d_in[5];
  const float* in_proj_b = (const float*)d_in[6];
  const float* out_w     = (const float*)d_in[7];
  const float* out_b     = (const float*)d_in[8];
  const float* w1        = (const float*)d_in[9];
  const float* b1        = (const float*)d_in[10];
  const float* w2        = (const float*)d_in[11];
  const float* b2        = (const float*)d_in[12];
  float* out = (float*)d_out;

  char* ws = (char*)d_ws;
  unsigned short* h    = (unsigned short*)(ws);                 //  8 MiB  LN1 out bf16
  unsigned short* wqkv = (unsigned short*)(ws + (8u << 20));    //  6 MiB
  unsigned short* wout = (unsigned short*)(ws + (14u << 20));   //  2 MiB
  unsigned short* w1b  = (unsigned short*)(ws + (16u << 20));   //  8 MiB
  unsigned short* w2b  = (unsigned short*)(ws + (24u << 20));   //  8 MiB
  unsigned short* qkv  = (unsigned short*)(ws + (32u << 20));   // 24 MiB
  unsigned short* aout = (unsigned short*)(ws + (56u << 20));   //  8 MiB
  unsigned short* h2   = (unsigned short*)(ws + (64u << 20));   //  8 MiB bf16
  unsigned short* m_in = (unsigned short*)(ws + (80u << 20));   //  8 MiB
  unsigned short* act  = (unsigned short*)(ws + (88u << 20));   // 32 MiB (ends 120 MiB)
  unsigned short* part_op = (unsigned short*)(ws + (88u << 20)); // 32 MiB, act region (dead until MLP1)
  unsigned short* part_m2 = (unsigned short*)(ws + (32u << 20)); // 32 MiB, qkv+aout region (dead after out-proj)
  unsigned short* vT   = (unsigned short*)(ws + (128u << 20));  //  8 MiB V^T [1024][4096]

  // 1: weight cvt + LN1 (merged)
  prep<<<dim3(CVT_BLOCKS + TOK), 256, 0, stream>>>(
      in_proj_w, out_w, w1, w2, wqkv, wout, w1b, w2b, x, ln1_w, ln1_b, h);

  // 2: QKV 256^2, grid 192, NT=16; also emits transposed V
  gemm256<0, 0, 16, 1><<<dim3(16 * 12), 512, 0, stream>>>(
      h, wqkv, in_proj_b, qkv, 4096, 3072, 1024, vT);

  // 3: attention (V from vT via gload_lds)
  attn_win<<<dim3(32, 16), 256, 0, stream>>>(qkv, vT, aout);

  // 4: out-proj split-K=4 (grid 64x4, NT=4) -> partials
  gemm256<0, 1, 4, 0><<<dim3(16 * 4, 4), 512, 0, stream>>>(
      aout, wout, nullptr, part_op, 4096, 1024, 1024, nullptr);

  // 5: reduce + residual + LN2 (h2 bf16)
  reduce_ln<<<dim3(TOK), 256, 0, stream>>>(part_op, x, out_b, ln2_w, ln2_b, h2, m_in, 4);

  // 6: MLP1 256^2 + relu, grid 256, NT=16
  gemm256<1, 0, 16, 0><<<dim3(16 * 16), 512, 0, stream>>>(
      m_in, w1b, b1, act, 4096, 4096, 1024, nullptr);

  // 7: MLP2 split-K=4 (grid 64x4, NT=16) -> partials
  gemm256<0, 1, 16, 0><<<dim3(16 * 4, 4), 512, 0, stream>>>(
      act, w2b, nullptr, part_m2, 4096, 1024, 4096, nullptr);

  // 8: reduce + bias + residual(bf16) -> fp32 out
  reduce_add<<<dim3(4096 * 1024 / 4 / 256), 256, 0, stream>>>(
      part_m2, h2, b2, out, 4096 * 1024, 1024, 4);
}

// Round 17
// 186.131 us; speedup vs baseline: 1.0097x; 1.0097x over previous
//
#include <hip/hip_runtime.h>

#define TOK 4096
#define EMB 1024

typedef __attribute__((ext_vector_type(8))) short s16x8;
typedef __attribute__((ext_vector_type(4))) float f32x4;

__device__ __forceinline__ unsigned short f2bf(float f) {
  union { float f; unsigned int u; } v; v.f = f;
  unsigned int r = v.u + 0x7FFFu + ((v.u >> 16) & 1u);
  return (unsigned short)(r >> 16);
}
__device__ __forceinline__ float bf2f(unsigned short u) {
  union { unsigned int u; float f; } v; v.u = ((unsigned int)u) << 16; return v.f;
}

#define GLOAD_LDS16(g, l) __builtin_amdgcn_global_load_lds( \
    (const __attribute__((address_space(1))) void*)(g), \
    (__attribute__((address_space(3))) void*)(l), 16, 0, 0)

// =================== 256x256 GEMM (round-9 core, FROZEN at ~868 TF)
// 512 threads = 8 waves (2M x 4N), per-wave out 128x64, BK=64, dbuf LDS 128KB.
// NT template -> fully unrolled K-loop, hoisted LDS read bases (kt&1)<<15.
// PART: 0 = bias(+relu) -> bf16 store; 1 = bf16 partial store at C + y*M*N.
// VTR:  1 = QKV mode: V third (cols >= 2048) goes ONLY to vT[dcol][token]
//       (transposed, ushort4 over 4 tokens); qkv's V third is never read.
// Round-10 lesson: fp32 atomicAdd epilogue = 2x kernel time (L2 RMW). Do not revisit.
// Round-13 lesson: cooperative grid.sync()+in-kernel reduce = 4x GEMM slowdown.
// Round-15 lesson: swizzle read must XOR the FULL slot index (rule #21).
template<int RELU, int PART, int NT, int VTR>
__global__ __launch_bounds__(512)
void gemm256(const unsigned short* __restrict__ A,
             const unsigned short* __restrict__ B,
             const float* __restrict__ bias,
             unsigned short* __restrict__ C, int M, int N, int K,
             unsigned short* __restrict__ vT)
{
  __shared__ unsigned short lds[2][2][128 * 128];  // [matrix][buf][16384 shorts]
  const int tid = threadIdx.x;
  const int lane = tid & 63;
  const int w = tid >> 6;
  const int wr = w >> 2, wc = w & 3;
  const int l15 = lane & 15, lhi = lane >> 4;
  const int nbm = M >> 8;
  const int bm = blockIdx.x % nbm, bn = blockIdx.x / nbm;
  const int m0 = bm << 8, n0 = bn << 8;
  const int k0 = blockIdx.y * (NT * 64);

  const char* Abase = (const char*)(A + (size_t)m0 * K) + (size_t)k0 * 2;
  const char* Bbase = (const char*)(B + (size_t)n0 * K) + (size_t)k0 * 2;
  const size_t rowb = (size_t)K * 2;

  const int srt = tid >> 3;
  const int sccx = ((tid & 7) << 4) ^ ((srt & 7) << 4);
  const char* gA = Abase + (size_t)srt * rowb + sccx;
  const char* gB = Bbase + (size_t)srt * rowb + sccx;

  auto STAGE_A = [&](int ktl, int h, int p) {
    char* d = (char*)&lds[0][0][0] + p * 32768 + h * 16384 + (w << 10);
    const char* g = gA + (size_t)(h * 128) * rowb + ktl * 128;
    GLOAD_LDS16(g, d);
    GLOAD_LDS16(g + 64 * rowb, d + 8192);
  };
  auto STAGE_B = [&](int ktl, int h, int p) {
    char* d = (char*)&lds[1][0][0] + p * 32768 + h * 16384 + (w << 10);
    const char* g = gB + (size_t)(h * 128) * rowb + ktl * 128;
    GLOAD_LDS16(g, d);
    GLOAD_LDS16(g + 64 * rowb, d + 8192);
  };

  const int rdxor = (l15 & 7) << 4;
  const char* pA0 = (const char*)&lds[0][0][0] + (wr * 128 + l15) * 128 + ((0 * 64 + lhi * 16) ^ rdxor);
  const char* pA1 = (const char*)&lds[0][0][0] + (wr * 128 + l15) * 128 + ((1 * 64 + lhi * 16) ^ rdxor);
  const char* pB0 = (const char*)&lds[1][0][0] + (wc * 64 + l15) * 128 + ((0 * 64 + lhi * 16) ^ rdxor);
  const char* pB1 = (const char*)&lds[1][0][0] + (wc * 64 + l15) * 128 + ((1 * 64 + lhi * 16) ^ rdxor);

  f32x4 acc[8][4];
#pragma unroll
  for (int mf = 0; mf < 8; ++mf)
#pragma unroll
    for (int nf = 0; nf < 4; ++nf)
#pragma unroll
      for (int j = 0; j < 4; ++j) acc[mf][nf][j] = 0.f;

  STAGE_A(0, 0, 0); STAGE_A(0, 1, 0);
  STAGE_B(0, 0, 0); STAGE_B(0, 1, 0);
  STAGE_A(1, 0, 1); STAGE_A(1, 1, 1);
  STAGE_B(1, 0, 1);
  asm volatile("s_waitcnt vmcnt(6)" ::: "memory");
  __builtin_amdgcn_s_barrier();

  s16x8 af[8][2], bf[4][2];

#pragma unroll
  for (int kt = 0; kt < NT; ++kt) {
    const int P = (kt & 1) << 15;
    const int p = kt & 1;

#pragma unroll
    for (int mi = 0; mi < 4; ++mi) {
      af[mi][0] = *(const s16x8*)(pA0 + mi * 2048 + P);
      af[mi][1] = *(const s16x8*)(pA1 + mi * 2048 + P);
    }
#pragma unroll
    for (int ni = 0; ni < 2; ++ni) {
      bf[ni][0] = *(const s16x8*)(pB0 + ni * 2048 + P);
      bf[ni][1] = *(const s16x8*)(pB1 + ni * 2048 + P);
    }
#pragma unroll
    for (int mi = 4; mi < 8; ++mi) {
      af[mi][0] = *(const s16x8*)(pA0 + mi * 2048 + P);
      af[mi][1] = *(const s16x8*)(pA1 + mi * 2048 + P);
    }
#pragma unroll
    for (int ni = 2; ni < 4; ++ni) {
      bf[ni][0] = *(const s16x8*)(pB0 + ni * 2048 + P);
      bf[ni][1] = *(const s16x8*)(pB1 + ni * 2048 + P);
    }

    if (kt + 1 < NT) STAGE_B(kt + 1, 1, p ^ 1);

    __builtin_amdgcn_s_setprio(1);
#pragma unroll
    for (int mi = 0; mi < 4; ++mi)
#pragma unroll
      for (int ni = 0; ni < 2; ++ni)
#pragma unroll
        for (int ks = 0; ks < 2; ++ks)
          acc[mi][ni] = __builtin_amdgcn_mfma_f32_16x16x32_bf16(af[mi][ks], bf[ni][ks], acc[mi][ni], 0, 0, 0);
#pragma unroll
    for (int mi = 4; mi < 8; ++mi)
#pragma unroll
      for (int ni = 0; ni < 2; ++ni)
#pragma unroll
        for (int ks = 0; ks < 2; ++ks)
          acc[mi][ni] = __builtin_amdgcn_mfma_f32_16x16x32_bf16(af[mi][ks], bf[ni][ks], acc[mi][ni], 0, 0, 0);
#pragma unroll
    for (int mi = 0; mi < 4; ++mi)
#pragma unroll
      for (int ni = 2; ni < 4; ++ni)
#pragma unroll
        for (int ks = 0; ks < 2; ++ks)
          acc[mi][ni] = __builtin_amdgcn_mfma_f32_16x16x32_bf16(af[mi][ks], bf[ni][ks], acc[mi][ni], 0, 0, 0);
#pragma unroll
    for (int mi = 4; mi < 8; ++mi)
#pragma unroll
      for (int ni = 2; ni < 4; ++ni)
#pragma unroll
        for (int ks = 0; ks < 2; ++ks)
          acc[mi][ni] = __builtin_amdgcn_mfma_f32_16x16x32_bf16(af[mi][ks], bf[ni][ks], acc[mi][ni], 0, 0, 0);
    __builtin_amdgcn_s_setprio(0);

    __builtin_amdgcn_s_barrier();

    if (kt + 2 < NT) {
      STAGE_A(kt + 2, 0, p);
      STAGE_A(kt + 2, 1, p);
      STAGE_B(kt + 2, 0, p);
    }

    if (kt + 1 < NT) {
      if (kt + 2 < NT) asm volatile("s_waitcnt vmcnt(6)" ::: "memory");
      else             asm volatile("s_waitcnt vmcnt(0)" ::: "memory");
      __builtin_amdgcn_s_barrier();
    }
  }

  // ---- epilogue
  unsigned short* Cw = PART ? C + (size_t)blockIdx.y * M * N : C;
#pragma unroll
  for (int mf = 0; mf < 8; ++mf) {
    const int row = m0 + wr * 128 + mf * 16 + lhi * 4;
#pragma unroll
    for (int nf = 0; nf < 4; ++nf) {
      const int col = n0 + wc * 64 + nf * 16 + l15;
      const float bv = PART ? 0.f : bias[col];
      const bool vthird = VTR && (col >= 2048);
      ushort4 pk;
#pragma unroll
      for (int j = 0; j < 4; ++j) {
        float v = acc[mf][nf][j] + bv;
        if (RELU) v = fmaxf(v, 0.f);
        const unsigned short bb = f2bf(v);
        if (!vthird)
          Cw[(size_t)(row + j) * N + col] = bb;
        else { if (j == 0) pk.x = bb; else if (j == 1) pk.y = bb; else if (j == 2) pk.z = bb; else pk.w = bb; }
      }
      if (vthird) {
        const int dcol = col - 2048;
        *(ushort4*)(vT + (size_t)dcol * 4096 + row) = pk;
      }
    }
  }
}

// ---------------- reduce split-K partials + bias + residual(bf16) -> fp32 out
__global__ __launch_bounds__(256)
void reduce_add(const unsigned short* __restrict__ part, const unsigned short* __restrict__ res,
                const float* __restrict__ bias, float* __restrict__ out,
                int MN, int N, int S)
{
  const int i4 = (blockIdx.x * 256 + threadIdx.x) * 4;
  if (i4 >= MN) return;
  const int col = i4 & (N - 1);
  const ushort4 r = *(const ushort4*)(res + i4);
  float4 v;
  v.x = bf2f(r.x) + bias[col];
  v.y = bf2f(r.y) + bias[col + 1];
  v.z = bf2f(r.z) + bias[col + 2];
  v.w = bf2f(r.w) + bias[col + 3];
  for (int s = 0; s < S; ++s) {
    const ushort4 p = *(const ushort4*)(part + (size_t)s * MN + i4);
    v.x += bf2f(p.x); v.y += bf2f(p.y); v.z += bf2f(p.z); v.w += bf2f(p.w);
  }
  *(float4*)(out + i4) = v;
}

// ---------------- reduce out-proj partials + bias + residual, then LayerNorm2
__global__ __launch_bounds__(256)
void reduce_ln(const unsigned short* __restrict__ part, const float* __restrict__ x,
               const float* __restrict__ ob, const float* __restrict__ ln_w,
               const float* __restrict__ ln_b, unsigned short* __restrict__ h2,
               unsigned short* __restrict__ m_in, int S)
{
  const int row = blockIdx.x;
  const int t = threadIdx.x;
  const size_t off = (size_t)row * EMB + t * 4;
  float4 v = *(const float4*)(x + off);
  const float4 obv = ((const float4*)ob)[t];
  v.x += obv.x; v.y += obv.y; v.z += obv.z; v.w += obv.w;
  for (int s = 0; s < S; ++s) {
    const ushort4 p = *(const ushort4*)(part + (size_t)s * TOK * EMB + off);
    v.x += bf2f(p.x); v.y += bf2f(p.y); v.z += bf2f(p.z); v.w += bf2f(p.w);
  }
  ushort4 hb;
  hb.x = f2bf(v.x); hb.y = f2bf(v.y); hb.z = f2bf(v.z); hb.w = f2bf(v.w);
  *(ushort4*)(h2 + off) = hb;

  float s1 = v.x + v.y + v.z + v.w;
  float sq = v.x * v.x + v.y * v.y + v.z * v.z + v.w * v.w;
#pragma unroll
  for (int o = 1; o < 64; o <<= 1) { s1 += __shfl_xor(s1, o); sq += __shfl_xor(sq, o); }
  __shared__ float red[8];
  if ((t & 63) == 0) { red[t >> 6] = s1; red[4 + (t >> 6)] = sq; }
  __syncthreads();
  s1 = red[0] + red[1] + red[2] + red[3];
  sq = red[4] + red[5] + red[6] + red[7];
  const float mu = s1 * (1.f / EMB);
  const float rs = rsqrtf(sq * (1.f / EMB) - mu * mu + 1e-5f);
  const float4 wv = ((const float4*)ln_w)[t];
  const float4 bv = ((const float4*)ln_b)[t];
  ushort4 o;
  o.x = f2bf((v.x - mu) * rs * wv.x + bv.x);
  o.y = f2bf((v.y - mu) * rs * wv.y + bv.y);
  o.z = f2bf((v.z - mu) * rs * wv.z + bv.z);
  o.w = f2bf((v.w - mu) * rs * wv.w + bv.w);
  ((ushort4*)(m_in + (size_t)row * EMB))[t] = o;
}

// ---------------- prep: weight cvt (4 matrices) + LayerNorm1, one launch
#define Q0 786432
#define Q1 (Q0 + 262144)
#define Q2 (Q1 + 1048576)
#define Q3 (Q2 + 1048576)
#define CVT_BLOCKS (Q3 / 256)   // 12288
__global__ __launch_bounds__(256)
void prep(const float* __restrict__ w0, const float* __restrict__ w1s,
          const float* __restrict__ w2s, const float* __restrict__ w3s,
          unsigned short* __restrict__ d0, unsigned short* __restrict__ d1,
          unsigned short* __restrict__ d2, unsigned short* __restrict__ d3,
          const float* __restrict__ x, const float* __restrict__ ln_w,
          const float* __restrict__ ln_b, unsigned short* __restrict__ h)
{
  __shared__ float red[8];
  const int bid = blockIdx.x;
  const int t = threadIdx.x;
  if (bid < CVT_BLOCKS) {
    const int i = bid * 256 + t;
    const float* s; unsigned short* d; int off;
    if (i < Q0)      { s = w0;  d = d0; off = i; }
    else if (i < Q1) { s = w1s; d = d1; off = i - Q0; }
    else if (i < Q2) { s = w2s; d = d2; off = i - Q1; }
    else             { s = w3s; d = d3; off = i - Q2; }
    const float4 v = ((const float4*)s)[off];
    ushort4 o;
    o.x = f2bf(v.x); o.y = f2bf(v.y); o.z = f2bf(v.z); o.w = f2bf(v.w);
    ((ushort4*)d)[off] = o;
    return;
  }
  const int row = bid - CVT_BLOCKS;
  const float4 v = ((const float4*)(x + (size_t)row * EMB))[t];
  float sm = v.x + v.y + v.z + v.w;
  float sq = v.x * v.x + v.y * v.y + v.z * v.z + v.w * v.w;
#pragma unroll
  for (int off = 1; off < 64; off <<= 1) { sm += __shfl_xor(sm, off); sq += __shfl_xor(sq, off); }
  if ((t & 63) == 0) { red[t >> 6] = sm; red[4 + (t >> 6)] = sq; }
  __syncthreads();
  sm = red[0] + red[1] + red[2] + red[3];
  sq = red[4] + red[5] + red[6] + red[7];
  const float mu = sm * (1.f / EMB);
  const float rs = rsqrtf(sq * (1.f / EMB) - mu * mu + 1e-5f);
  const float4 wv = ((const float4*)ln_w)[t];
  const float4 bv = ((const float4*)ln_b)[t];
  ushort4 o;
  o.x = f2bf((v.x - mu) * rs * wv.x + bv.x);
  o.y = f2bf((v.y - mu) * rs * wv.y + bv.y);
  o.z = f2bf((v.z - mu) * rs * wv.z + bv.z);
  o.w = f2bf((v.w - mu) * rs * wv.w + bv.w);
  ((ushort4*)(h + (size_t)row * EMB))[t] = o;
}

// ---------------- sliding-window causal attention, flash-style
// V staged via global_load_lds from pre-transposed vT. LDS[d][slot s] holds
// global slot g = s ^ (d&7); reads use s = (ks*4+lhi) ^ (d&7) (full-index XOR).
__global__ __launch_bounds__(256)
void attn_win(const unsigned short* __restrict__ qkv, const unsigned short* __restrict__ vT,
              unsigned short* __restrict__ aout)
{
  __shared__ unsigned short Ks[64 * 136];   // K tile, padded
  __shared__ unsigned short Vt[128 * 64];   // V^T tile [d][t], swizzled, 16KB
  __shared__ unsigned short Ps[4 * 16 * 72];
  const int bh = blockIdx.y;
  const int b = bh >> 3, hh = bh & 7;
  const int q0 = blockIdx.x << 6;
  const int tid = threadIdx.x, lane = tid & 63, w = tid >> 6;
  const int l15 = lane & 15, lhi = lane >> 4;
  const size_t base = (size_t)b * 2048 * 3072;

  s16x8 qf[4];
  {
    const unsigned short* qp = qkv + base + (size_t)(q0 + w * 16 + l15) * 3072 + hh * 128 + lhi * 8;
#pragma unroll
    for (int ks = 0; ks < 4; ++ks) qf[ks] = *(const s16x8*)(qp + ks * 32);
  }

  const int vrow = tid >> 3;
  const int vcol = (((tid & 7) ^ ((tid >> 3) & 7)) << 4);
  const char* vTbase = (const char*)(vT + (size_t)(hh * 128 + vrow) * 4096) + vcol;
  char* vdst = (char*)&Vt[0] + (w << 10);
  const char* pVrow = (const char*)&Vt[0] + l15 * 128;
  const int vxor = (l15 & 7) << 4;

  f32x4 o[8];
#pragma unroll
  for (int n = 0; n < 8; ++n)
#pragma unroll
    for (int j = 0; j < 4; ++j) o[n][j] = 0.f;
  float mrow[4] = {-1e30f, -1e30f, -1e30f, -1e30f};
  float lrow[4] = {0.f, 0.f, 0.f, 0.f};

  for (int t = 0; t < 5; ++t) {
    const int kt0 = q0 - 256 + t * 64;
    if (kt0 < 0) continue;
    __syncthreads();
    {
      const unsigned short* kg = qkv + base + (size_t)kt0 * 3072 + 1024 + hh * 128;
#pragma unroll
      for (int i = 0; i < 4; ++i) {
        const int c = tid + i * 256;
        const int r = c >> 4, cc = (c & 15) << 3;
        *(s16x8*)(Ks + r * 136 + cc) = *(const s16x8*)(kg + (size_t)r * 3072 + cc);
      }
      const char* vg = vTbase + (size_t)(b * 2048 + kt0) * 2;
#pragma unroll
      for (int c = 0; c < 4; ++c)
        GLOAD_LDS16(vg + (size_t)(c * 32) * 8192, vdst + c * 4096);
    }
    __syncthreads();

    f32x4 s[4];
#pragma unroll
    for (int n = 0; n < 4; ++n)
#pragma unroll
      for (int j = 0; j < 4; ++j) s[n][j] = 0.f;
    __builtin_amdgcn_s_setprio(1);
#pragma unroll
    for (int ks = 0; ks < 4; ++ks) {
#pragma unroll
      for (int n = 0; n < 4; ++n) {
        s16x8 kf = *(const s16x8*)(Ks + (n * 16 + l15) * 136 + ks * 32 + lhi * 8);
        s[n] = __builtin_amdgcn_mfma_f32_16x16x32_bf16(qf[ks], kf, s[n], 0, 0, 0);
      }
    }
    __builtin_amdgcn_s_setprio(0);
    const bool mlo = (t == 0);
    const bool mhi = (kt0 == q0);
#pragma unroll
    for (int n = 0; n < 4; ++n) {
      const int kcol = n * 16 + l15;
#pragma unroll
      for (int j = 0; j < 4; ++j) {
        const int qrow = w * 16 + lhi * 4 + j;
        float v = s[n][j] * 0.08838834764831845f;
        if ((mlo && kcol < qrow) || (mhi && kcol > qrow)) v = -1e30f;
        s[n][j] = v;
      }
    }
    float alpha[4];
#pragma unroll
    for (int j = 0; j < 4; ++j) {
      float mx = fmaxf(fmaxf(s[0][j], s[1][j]), fmaxf(s[2][j], s[3][j]));
#pragma unroll
      for (int off = 1; off < 16; off <<= 1) mx = fmaxf(mx, __shfl_xor(mx, off));
      const float mn = fmaxf(mrow[j], mx);
      alpha[j] = __expf(mrow[j] - mn);
      mrow[j] = mn;
    }
    float rowsum[4] = {0.f, 0.f, 0.f, 0.f};
#pragma unroll
    for (int n = 0; n < 4; ++n)
#pragma unroll
      for (int j = 0; j < 4; ++j) {
        const float p = __expf(s[n][j] - mrow[j]);
        rowsum[j] += p;
        Ps[(w * 16 + lhi * 4 + j) * 72 + n * 16 + l15] = f2bf(p);
      }
#pragma unroll
    for (int j = 0; j < 4; ++j) {
      float rs = rowsum[j];
#pragma unroll
      for (int off = 1; off < 16; off <<= 1) rs += __shfl_xor(rs, off);
      lrow[j] = lrow[j] * alpha[j] + rs;
    }
#pragma unroll
    for (int n = 0; n < 8; ++n)
#pragma unroll
      for (int j = 0; j < 4; ++j) o[n][j] *= alpha[j];
    __builtin_amdgcn_s_setprio(1);
#pragma unroll
    for (int ks = 0; ks < 2; ++ks) {
      const s16x8 pf = *(const s16x8*)(Ps + (w * 16 + l15) * 72 + ks * 32 + lhi * 8);
      const int cc = (ks * 64 + lhi * 16) ^ vxor;
#pragma unroll
      for (int n = 0; n < 8; ++n) {
        const s16x8 vf = *(const s16x8*)(pVrow + n * 2048 + cc);
        o[n] = __builtin_amdgcn_mfma_f32_16x16x32_bf16(pf, vf, o[n], 0, 0, 0);
      }
    }
    __builtin_amdgcn_s_setprio(0);
  }
  unsigned short* op = aout + (size_t)(b * 2048 + q0 + w * 16) * 1024 + hh * 128;
#pragma unroll
  for (int n = 0; n < 8; ++n)
#pragma unroll
    for (int j = 0; j < 4; ++j)
      op[(size_t)(lhi * 4 + j) * 1024 + n * 16 + l15] = f2bf(o[n][j] / lrow[j]);
}

extern "C" void kernel_launch(void* const* d_in, const int* in_sizes, int n_in,
                              void* d_out, int out_size, void* d_ws, size_t ws_size,
                              hipStream_t stream)
{
  (void)in_sizes; (void)n_in; (void)out_size; (void)ws_size;
  const float* x         = (const float*)d_in[0];
  const float* ln1_w     = (const float*)d_in[1];
  const float* ln1_b     = (const float*)d_in[2];
  const float* ln2_w     = (const float*)d_in[3];
  const float* ln2_b     = (const float*)d_in[4];
  const float* in_proj_w = (const float*)d_in[5];
  const float* in_proj_b = (const float*)d_in[6];
  const float* out_w     = (const float*)d_in[7];
  const float* out_b     = (const float*)d_in[8];
  const float* w1        = (const float*)d_in[9];
  const float* b1        = (const float*)d_in[10];
  const float* w2        = (const float*)d_in[11];
  const float* b2        = (const float*)d_in[12];
  float* out = (float*)d_out;

  char* ws = (char*)d_ws;
  unsigned short* h    = (unsigned short*)(ws);                 //  8 MiB  LN1 out bf16
  unsigned short* wqkv = (unsigned short*)(ws + (8u << 20));    //  6 MiB
  unsigned short* wout = (unsigned short*)(ws + (14u << 20));   //  2 MiB
  unsigned short* w1b  = (unsigned short*)(ws + (16u << 20));   //  8 MiB
  unsigned short* w2b  = (unsigned short*)(ws + (24u << 20));   //  8 MiB
  unsigned short* qkv  = (unsigned short*)(ws + (32u << 20));   // 24 MiB (V third unused)
  unsigned short* aout = (unsigned short*)(ws + (56u << 20));   //  8 MiB
  unsigned short* h2   = (unsigned short*)(ws + (64u << 20));   //  8 MiB bf16
  unsigned short* m_in = (unsigned short*)(ws + (80u << 20));   //  8 MiB
  unsigned short* act  = (unsigned short*)(ws + (88u << 20));   // 32 MiB (ends 120 MiB)
  unsigned short* part_op = (unsigned short*)(ws + (88u << 20)); // 32 MiB, act region (dead until MLP1)
  unsigned short* part_m2 = (unsigned short*)(ws + (32u << 20)); // 32 MiB, qkv+aout region (dead after out-proj)
  unsigned short* vT   = (unsigned short*)(ws + (128u << 20));  //  8 MiB V^T [1024][4096]

  // 1: weight cvt + LN1 (merged)
  prep<<<dim3(CVT_BLOCKS + TOK), 256, 0, stream>>>(
      in_proj_w, out_w, w1, w2, wqkv, wout, w1b, w2b, x, ln1_w, ln1_b, h);

  // 2: QKV 256^2, grid 192, NT=16; V third -> vT only
  gemm256<0, 0, 16, 1><<<dim3(16 * 12), 512, 0, stream>>>(
      h, wqkv, in_proj_b, qkv, 4096, 3072, 1024, vT);

  // 3: attention (V from vT via gload_lds)
  attn_win<<<dim3(32, 16), 256, 0, stream>>>(qkv, vT, aout);

  // 4: out-proj split-K=4 (grid 64x4, NT=4) -> partials
  gemm256<0, 1, 4, 0><<<dim3(16 * 4, 4), 512, 0, stream>>>(
      aout, wout, nullptr, part_op, 4096, 1024, 1024, nullptr);

  // 5: reduce + residual + LN2 (h2 bf16)
  reduce_ln<<<dim3(TOK), 256, 0, stream>>>(part_op, x, out_b, ln2_w, ln2_b, h2, m_in, 4);

  // 6: MLP1 256^2 + relu, grid 256, NT=16
  gemm256<1, 0, 16, 0><<<dim3(16 * 16), 512, 0, stream>>>(
      m_in, w1b, b1, act, 4096, 4096, 1024, nullptr);

  // 7: MLP2 split-K=4 (grid 64x4, NT=16) -> partials
  gemm256<0, 1, 16, 0><<<dim3(16 * 4, 4), 512, 0, stream>>>(
      act, w2b, nullptr, part_m2, 4096, 1024, 4096, nullptr);

  // 8: reduce + bias + residual(bf16) -> fp32 out
  reduce_add<<<dim3(4096 * 1024 / 4 / 256), 256, 0, stream>>>(
      part_m2, h2, b2, out, 4096 * 1024, 1024, 4);
}